// Round 2
// baseline (196.231 us; speedup 1.0000x reference)
//
#include <hip/hip_runtime.h>

// crossCorrelation3D: local (9x9x9) normalized cross-correlation loss, fused.
// B=2, C=1, D=H=W=160, fp32. Output = -mean(cc), scalar.
//
// R2: throughput-bound on LDS pipe + barriers (R1 post-mortem: time tracks
// total plane-work, not blocks/CU; step3 used 80/256 threads).
//  1. DCHUNK back to 32 (1000 blocks, minimum plane redundancy 1.25x).
//  2. step3+ring FUSED: each thread sums its own 9 rows of tmp5 per field
//     (45 b32 reads, 2-way banks = free). Removes Pbuf (-5.3KB LDS), one
//     barrier (3->2 per plane), and the 80-thread serial phase.
//  3. Keep T14 register prefetch (next halo plane + flow).
//
// NOTE: reference transforms target t=(raw+1)/2 BEFORE zero-padded box sum,
// so padding must contribute t=0 (not 0.5). Transform applied at load time
// for in-bounds voxels only; out-of-range D planes contribute pn=0 via the
// block-uniform 'valid' flag (their stage/step2 are skipped).

constexpr int NB = 2;
constexpr int ND = 160;
constexpr int NH = 160;
constexpr int NW = 160;
constexpr int TH = 16;
constexpr int TW = 16;
constexpr int DCHUNK = 32;
constexpr int NDCH = ND / DCHUNK;            // 5
constexpr int NPL = DCHUNK + 8;              // 40 planes marched per block
constexpr int FS5 = 392;                     // tmp5 field stride (24*16 + 8 pad)
constexpr float INV_K = 1.0f / 729.0f;
constexpr double INV_COUNT = 1.0 / (double(NB) * ND * NH * NW); // 1/8192000

// Issue global loads of one 24x24 halo plane (input & target) into registers.
// tid<144: each thread owns one float4 of the 24x(6*float4) plane.
// w0-4 is a multiple of 4 so rows are float4-aligned; each 4-wide segment is
// entirely in-bounds or entirely out (w0 % 16 == 0, halo = 4).
__device__ __forceinline__ void issue_load(
    const float* __restrict__ in, const float* __restrict__ tg,
    int b, int dp, int h0, int w0, int tid,
    float4& iv, float4& tv)
{
    iv = make_float4(0.f, 0.f, 0.f, 0.f);
    tv = make_float4(0.f, 0.f, 0.f, 0.f);
    if (tid < 144 && ((unsigned)dp < (unsigned)ND)) {
        int r = tid / 6;
        int q = tid - r * 6;
        int gh = h0 - 4 + r;
        int gw = w0 - 4 + q * 4;
        if (((unsigned)gh < (unsigned)NH) && ((unsigned)gw < (unsigned)NW)) {
            int base = ((b * ND + dp) * NH + gh) * NW + gw;   // fits int32
            iv = *reinterpret_cast<const float4*>(in + base);
            float4 rv = *reinterpret_cast<const float4*>(tg + base);
            tv.x = fmaf(rv.x, 0.5f, 0.5f);
            tv.y = fmaf(rv.y, 0.5f, 0.5f);
            tv.z = fmaf(rv.z, 0.5f, 0.5f);
            tv.w = fmaf(rv.w, 0.5f, 0.5f);
        }
    }
}

__device__ __forceinline__ void stage(int tid, const float4& iv, const float4& tv,
                                      float* __restrict__ inT, float* __restrict__ tgT)
{
    if (tid < 144) {
        reinterpret_cast<float4*>(inT)[tid] = iv;   // row stride 24 floats = 6 float4
        reinterpret_cast<float4*>(tgT)[tid] = tv;
    }
}

// w-direction 9-sums of 5 product fields -> tmp5[5][24][16] (field stride FS5)
__device__ __forceinline__ void step2(int tid, const float* __restrict__ inT,
                                      const float* __restrict__ tgT,
                                      float* __restrict__ tmp5)
{
    int pos = tid;
    #pragma unroll
    for (int rep = 0; rep < 2; ++rep) {
        if (pos < 384) {
            int r = pos >> 4, wo = pos & 15;
            const float* ir = inT + r * 24 + wo;
            const float* tr = tgT + r * 24 + wo;
            float s0 = 0.f, s1 = 0.f, s2 = 0.f, s3 = 0.f, s4 = 0.f;
            #pragma unroll
            for (int k = 0; k < 9; ++k) {
                float ivv = ir[k];
                float t = tr[k];            // already transformed (pad=0)
                s0 += t;
                s1 += ivv;
                s2 = fmaf(t, t, s2);
                s3 = fmaf(ivv, ivv, s3);
                s4 = fmaf(ivv, t, s4);
            }
            int o = r * 16 + wo;
            tmp5[0 * FS5 + o] = s0;
            tmp5[1 * FS5 + o] = s1;
            tmp5[2 * FS5 + o] = s2;
            tmp5[3 * FS5 + o] = s3;
            tmp5[4 * FS5 + o] = s4;
        }
        pos += 256;
    }
}

__device__ __forceinline__ float cc_value(const float S[5], float flv)
{
    float wgt = 1.0f / (1.0f + __expf(-flv));   // sigmoid, GAMMA=1
    float Ts = S[0], Is = S[1], TTs = S[2], IIs = S[3], ITs = S[4];
    float Ihat = Is * INV_K;
    float That = Ts * INV_K;
    float cross = ITs - Ihat * Ts - That * Is + That * Ihat * 729.0f;
    float T_var = TTs - 2.0f * That * Ts + That * That * 729.0f;
    float I_var = IIs - 2.0f * Ihat * Is + Ihat * Ihat * 729.0f;
    return cross * cross * wgt / (T_var * I_var + 1e-5f);
}

__global__ void __launch_bounds__(256)
cc3d_main(const float* __restrict__ in, const float* __restrict__ tg,
          const float* __restrict__ fl, double* __restrict__ acc_out)
{
    __shared__ float inT[24 * 24];
    __shared__ float tgT[24 * 24];
    __shared__ float tmp5[5 * FS5];
    __shared__ float red[4];

    const int tid = threadIdx.x;
    const int w0 = blockIdx.x * TW;
    const int h0 = blockIdx.y * TH;
    const int bz = blockIdx.z;
    const int b  = bz / NDCH;
    const int d0 = (bz - b * NDCH) * DCHUNK;
    const int hh = tid >> 4, ww = tid & 15;

    // D-direction ring of 9 plane values per field, statically indexed
    // (slot = l mod 9 = li, compile-time inside the unrolled li loop).
    float ring[45];
    #pragma unroll
    for (int i = 0; i < 45; ++i) ring[i] = 0.f;
    float S[5] = {0.f, 0.f, 0.f, 0.f, 0.f};
    float acc = 0.f;

    // Pipeline prologue: loads for plane 0 (dp = d0-4) in flight.
    float4 iv, tv;
    issue_load(in, tg, b, d0 - 4, h0, w0, tid, iv, tv);

    // ---- march planes l = 0..NPL-1; outputs start at l = 8 ----
    for (int lb = 0; lb < NPL + 8; lb += 9) {   // lb = 0,9,18,27,36
        #pragma unroll
        for (int li = 0; li < 9; ++li) {
            const int l = lb + li;
            if (l < NPL) {                        // block-uniform guard
                const int dp = d0 - 4 + l;
                const bool valid = ((unsigned)dp < (unsigned)ND);  // block-uniform
                if (valid) stage(tid, iv, tv, inT, tgT);
                float4 niv, ntv;
                issue_load(in, tg, b, dp + 1, h0, w0, tid, niv, ntv);
                float flv = 0.f;
                if (l >= 8) {
                    int dout = d0 + l - 8;
                    int fidx = ((b * ND + dout) * NH + (h0 + hh)) * NW + (w0 + ww);
                    flv = fl[fidx];
                }
                __syncthreads();   // A: stage visible; prev plane's tmp5 reads done
                if (valid) step2(tid, inT, tgT, tmp5);
                __syncthreads();   // B: tmp5 visible; inT/tgT reads done
                // fused h-sum + ring update: all 256 threads, 45 b32 reads,
                // bank pattern (ww + 16*hh) mod 32 -> 2-way (free).
                #pragma unroll
                for (int f = 0; f < 5; ++f) {
                    float pn = 0.f;
                    if (valid) {
                        const float* bp = tmp5 + f * FS5 + hh * 16 + ww;
                        #pragma unroll
                        for (int k = 0; k < 9; ++k) pn += bp[k * 16];
                    }
                    S[f] += pn - ring[f * 9 + li];
                    ring[f * 9 + li] = pn;
                }
                if (l >= 8) acc += cc_value(S, flv);
                iv = niv; tv = ntv;
            }
        }
    }

    // ---- block reduction -> double atomic into workspace ----
    #pragma unroll
    for (int off = 32; off > 0; off >>= 1) acc += __shfl_down(acc, off);
    if ((tid & 63) == 0) red[tid >> 6] = acc;
    __syncthreads();
    if (tid == 0) {
        double v = (double)red[0] + (double)red[1] + (double)red[2] + (double)red[3];
        atomicAdd(acc_out, v);
    }
}

__global__ void cc3d_finalize(const double* __restrict__ acc, float* __restrict__ out)
{
    out[0] = (float)(-(acc[0] * INV_COUNT));
}

extern "C" void kernel_launch(void* const* d_in, const int* in_sizes, int n_in,
                              void* d_out, int out_size, void* d_ws, size_t ws_size,
                              hipStream_t stream)
{
    const float* in = (const float*)d_in[0];   // 'input'
    const float* tg = (const float*)d_in[1];   // 'target'
    const float* fl = (const float*)d_in[2];   // 'flow'
    float* out = (float*)d_out;
    double* acc = (double*)d_ws;

    hipMemsetAsync(d_ws, 0, sizeof(double), stream);  // graph-safe memset node

    dim3 grid(NW / TW, NH / TH, NB * NDCH);  // (10, 10, 10) = 1000 blocks
    cc3d_main<<<grid, dim3(256), 0, stream>>>(in, tg, fl, acc);
    cc3d_finalize<<<1, 1, 0, stream>>>(acc, out);
}

// Round 3
// 176.542 us; speedup vs baseline: 1.1115x; 1.1115x over previous
//
#include <hip/hip_runtime.h>

// crossCorrelation3D: local (9x9x9) normalized cross-correlation loss, fused.
// B=2, C=1, D=H=W=160, fp32. Output = -mean(cc), scalar.
//
// R3: kernel is LDS-instruction-throughput bound (R1/R2 post-mortems: time
// tracks total LDS wave-ops/plane; model 1900 cyc/plane matched 112us).
// Cut LDS wave-ops ~3x:
//  - step2 quad (96 thr, thread=(row,quad)): 3 b128 reads/array, register
//    sliding w-9-sums, 1 b128 write per field. Rows 16B-aligned.
//  - h-pass slide (80 thr, thread=(field,wq,hseg)): 12 b128 row reads,
//    register sliding h-9-sums, 4 b128 writes to Pbuf.
//  - row stride 20 floats, field strides 488/328: b128 accesses bank-even.
//  - 2-barrier pipeline: {ring+cc(l-2), stage(l)} |X| {step2(l), hpass(l-1),
//    prefetch(l+1)} |Y|. tmp5 double-buffered; inT/tgT/Pbuf single
//    (all hazards barrier-separated; checked pairwise).
//
// NOTE: reference transforms target t=(raw+1)/2 BEFORE zero-padded box sum,
// so padding must contribute t=0. Transform applied at load time for
// in-bounds voxels; OOB D planes: step2/hpass skipped, ring substitutes 0.

constexpr int NB = 2;
constexpr int ND = 160;
constexpr int NH = 160;
constexpr int NW = 160;
constexpr int TH = 16;
constexpr int TW = 16;
constexpr int DCHUNK = 32;
constexpr int NDCH = ND / DCHUNK;        // 5
constexpr int NPL = DCHUNK + 8;          // 40 planes per block
constexpr int NIT = NPL + 2;             // 42 pipeline iterations
constexpr int TRS = 20;                  // tmp5 row stride (floats, 80B: 16B-aligned, odd mult of 4)
constexpr int TFS = 24 * TRS + 8;        // 488: tmp5 field stride (mod 32 = 8)
constexpr int PRS = 20;                  // Pbuf row stride
constexpr int PFS = 16 * PRS + 8;        // 328: Pbuf field stride (mod 32 = 8)
constexpr float INV_K = 1.0f / 729.0f;
constexpr double INV_COUNT = 1.0 / (double(NB) * ND * NH * NW); // 1/8192000

// Issue global loads of one 24x24 halo plane (input & target) into registers.
// tid<144: thread owns one float4 of the 24x(6*float4) plane. w0-4 is a
// multiple of 4 so rows are float4-aligned; each 4-wide segment is entirely
// in-bounds or entirely out (w0 % 16 == 0, halo = 4).
__device__ __forceinline__ void issue_load(
    const float* __restrict__ in, const float* __restrict__ tg,
    int b, int dp, int h0, int w0, int tid,
    float4& iv, float4& tv)
{
    iv = make_float4(0.f, 0.f, 0.f, 0.f);
    tv = make_float4(0.f, 0.f, 0.f, 0.f);
    if (tid < 144 && ((unsigned)dp < (unsigned)ND)) {
        int r = tid / 6;
        int q = tid - r * 6;
        int gh = h0 - 4 + r;
        int gw = w0 - 4 + q * 4;
        if (((unsigned)gh < (unsigned)NH) && ((unsigned)gw < (unsigned)NW)) {
            int base = ((b * ND + dp) * NH + gh) * NW + gw;   // fits int32
            iv = *reinterpret_cast<const float4*>(in + base);
            float4 rv = *reinterpret_cast<const float4*>(tg + base);
            tv.x = fmaf(rv.x, 0.5f, 0.5f);
            tv.y = fmaf(rv.y, 0.5f, 0.5f);
            tv.z = fmaf(rv.z, 0.5f, 0.5f);
            tv.w = fmaf(rv.w, 0.5f, 0.5f);
        }
    }
}

__device__ __forceinline__ void stage(int tid, const float4& iv, const float4& tv,
                                      float* __restrict__ inT, float* __restrict__ tgT)
{
    if (tid < 144) {
        reinterpret_cast<float4*>(inT)[tid] = iv;   // row stride 24 floats = 6 float4
        reinterpret_cast<float4*>(tgT)[tid] = tv;
    }
}

// w-direction 9-sums, quad form. Thread (r,q): outputs wo=4q..4q+3 of row r
// need inputs 4q..4q+11 (3 b128 per array). Register sliding per field.
#define W9SLIDE(EXPR, FI)                                                  \
    {                                                                      \
        float p0 = (EXPR(0)), p1 = (EXPR(1)), p2 = (EXPR(2)),              \
              p3 = (EXPR(3)), p4 = (EXPR(4)), p5 = (EXPR(5)),              \
              p6 = (EXPR(6)), p7 = (EXPR(7)), p8 = (EXPR(8)),              \
              p9 = (EXPR(9)), p10 = (EXPR(10)), p11 = (EXPR(11));          \
        float s = p0 + p1 + p2 + p3 + p4 + p5 + p6 + p7 + p8;              \
        float4 o;                                                          \
        o.x = s; s += p9 - p0;                                             \
        o.y = s; s += p10 - p1;                                            \
        o.z = s; s += p11 - p2;                                            \
        o.w = s;                                                           \
        *reinterpret_cast<float4*>(outp + (FI) * TFS) = o;                 \
    }

__device__ __forceinline__ void step2q(int tid, const float* __restrict__ inT,
                                       const float* __restrict__ tgT,
                                       float* __restrict__ t5)
{
    if (tid < 96) {
        const int r = tid >> 2, q = tid & 3;
        const float4* ip = reinterpret_cast<const float4*>(inT + r * 24 + 4 * q);
        const float4* tp = reinterpret_cast<const float4*>(tgT + r * 24 + 4 * q);
        const float4 i0 = ip[0], i1 = ip[1], i2 = ip[2];
        const float4 t0 = tp[0], t1 = tp[1], t2 = tp[2];
        const float ia[12] = {i0.x, i0.y, i0.z, i0.w, i1.x, i1.y, i1.z, i1.w,
                              i2.x, i2.y, i2.z, i2.w};
        const float ta[12] = {t0.x, t0.y, t0.z, t0.w, t1.x, t1.y, t1.z, t1.w,
                              t2.x, t2.y, t2.z, t2.w};
        float* outp = t5 + r * TRS + 4 * q;
        #define E_T(j)  ta[j]
        #define E_I(j)  ia[j]
        #define E_TT(j) (ta[j] * ta[j])
        #define E_II(j) (ia[j] * ia[j])
        #define E_IT(j) (ia[j] * ta[j])
        W9SLIDE(E_T, 0)
        W9SLIDE(E_I, 1)
        W9SLIDE(E_TT, 2)
        W9SLIDE(E_II, 3)
        W9SLIDE(E_IT, 4)
        #undef E_T
        #undef E_I
        #undef E_TT
        #undef E_II
        #undef E_IT
    }
}

// h-direction 9-sums, sliding quad form. Thread (f,wq,hs): outputs
// ho=4hs..4hs+3 for field f, w-quad wq. Reads 12 rows as b128, slides.
__device__ __forceinline__ void hpass(int tid, const float* __restrict__ t5,
                                      float* __restrict__ Pb)
{
    if (tid < 80) {
        const int f = tid >> 4;
        const int rem = tid & 15;
        const int wq = rem >> 2, hs = rem & 3;
        const float* bp = t5 + f * TFS + hs * 4 * TRS + wq * 4;
        float4 r4[12];
        #pragma unroll
        for (int k = 0; k < 12; ++k)
            r4[k] = *reinterpret_cast<const float4*>(bp + k * TRS);
        float sx = r4[0].x, sy = r4[0].y, sz = r4[0].z, sw = r4[0].w;
        #pragma unroll
        for (int k = 1; k < 9; ++k) {
            sx += r4[k].x; sy += r4[k].y; sz += r4[k].z; sw += r4[k].w;
        }
        float* op = Pb + f * PFS + hs * 4 * PRS + wq * 4;
        *reinterpret_cast<float4*>(op) = make_float4(sx, sy, sz, sw);
        #pragma unroll
        for (int j = 1; j < 4; ++j) {
            sx += r4[8 + j].x - r4[j - 1].x;
            sy += r4[8 + j].y - r4[j - 1].y;
            sz += r4[8 + j].z - r4[j - 1].z;
            sw += r4[8 + j].w - r4[j - 1].w;
            *reinterpret_cast<float4*>(op + j * PRS) = make_float4(sx, sy, sz, sw);
        }
    }
}

__device__ __forceinline__ float cc_value(const float S[5], float flv)
{
    float wgt = 1.0f / (1.0f + __expf(-flv));   // sigmoid, GAMMA=1
    float Ts = S[0], Is = S[1], TTs = S[2], IIs = S[3], ITs = S[4];
    float Ihat = Is * INV_K;
    float That = Ts * INV_K;
    float cross = ITs - Ihat * Ts - That * Is + That * Ihat * 729.0f;
    float T_var = TTs - 2.0f * That * Ts + That * That * 729.0f;
    float I_var = IIs - 2.0f * Ihat * Is + Ihat * Ihat * 729.0f;
    return cross * cross * wgt / (T_var * I_var + 1e-5f);
}

__global__ void __launch_bounds__(256, 4)
cc3d_main(const float* __restrict__ in, const float* __restrict__ tg,
          const float* __restrict__ fl, double* __restrict__ acc_out)
{
    __shared__ __align__(16) float inT[24 * 24];
    __shared__ __align__(16) float tgT[24 * 24];
    __shared__ __align__(16) float tmp5[2][5 * TFS];
    __shared__ __align__(16) float Pb[5 * PFS];
    __shared__ float red[4];

    const int tid = threadIdx.x;
    const int w0 = blockIdx.x * TW;
    const int h0 = blockIdx.y * TH;
    const int bz = blockIdx.z;
    const int b  = bz / NDCH;
    const int d0 = (bz - b * NDCH) * DCHUNK;
    const int hh = tid >> 4, ww = tid & 15;

    // D-direction ring of 9 plane values per field, statically indexed
    // (slot = (l-2) mod 9 = (li+7) mod 9, compile-time in unrolled li loop).
    float ring[45];
    #pragma unroll
    for (int i = 0; i < 45; ++i) ring[i] = 0.f;
    float S[5] = {0.f, 0.f, 0.f, 0.f, 0.f};
    float acc = 0.f;
    float flv = 0.f, flv_next = 0.f;

    // Prologue: loads for plane 0 (dp = d0-4) in flight.
    float4 civ, ctv;
    issue_load(in, tg, b, d0 - 4, h0, w0, tid, civ, ctv);

    // Pipeline: iter l does ring+cc(l-2), stage(l), X, step2(l), hpass(l-1),
    // prefetch(l+1), Y.  l = 0..NIT-1 (42 iters).
    for (int lb = 0; lb < 45; lb += 9) {
        #pragma unroll
        for (int li = 0; li < 9; ++li) {
            const int l = lb + li;
            if (l < NIT) {                          // block-uniform
                // ---- ring + cc for plane l-2 (Pbuf written last iter) ----
                if (l >= 2) {
                    const int lm2 = l - 2;
                    const int dpz = d0 - 4 + lm2;
                    const bool vz = ((unsigned)dpz < (unsigned)ND);  // uniform
                    const int slot = (li + 7) % 9;   // compile-time
                    #pragma unroll
                    for (int f = 0; f < 5; ++f) {
                        float pn = vz ? Pb[f * PFS + hh * PRS + ww] : 0.f;
                        S[f] += pn - ring[f * 9 + slot];
                        ring[f * 9 + slot] = pn;
                    }
                    if (lm2 >= 8) acc += cc_value(S, flv);
                }
                // ---- stage plane l (regs loaded last iter; zeros if OOB) ----
                if (l < NPL) stage(tid, civ, ctv, inT, tgT);
                __syncthreads();                     // X
                // ---- step2 plane l -> tmp5[l&1] ----
                if (l < NPL) {
                    const int dpl = d0 - 4 + l;
                    if ((unsigned)dpl < (unsigned)ND)       // block-uniform
                        step2q(tid, inT, tgT, tmp5[l & 1]);
                }
                // ---- h-pass plane l-1: tmp5[(l-1)&1] -> Pbuf ----
                if (l >= 1 && l <= NPL) {
                    const int dph = d0 - 4 + (l - 1);
                    if ((unsigned)dph < (unsigned)ND)       // block-uniform
                        hpass(tid, tmp5[(l - 1) & 1], Pb);
                }
                // ---- prefetch plane l+1 (regs) + flow for next iter's cc ----
                float4 niv = make_float4(0.f, 0.f, 0.f, 0.f), ntv = niv;
                if (l + 1 < NPL)
                    issue_load(in, tg, b, d0 - 4 + (l + 1), h0, w0, tid, niv, ntv);
                if (l >= 9 && l <= 40) {
                    int dout = d0 + (l - 9);
                    flv_next = fl[((b * ND + dout) * NH + (h0 + hh)) * NW + (w0 + ww)];
                }
                __syncthreads();                     // Y
                civ = niv; ctv = ntv; flv = flv_next;
            }
        }
    }

    // ---- block reduction -> double atomic into workspace ----
    #pragma unroll
    for (int off = 32; off > 0; off >>= 1) acc += __shfl_down(acc, off);
    if ((tid & 63) == 0) red[tid >> 6] = acc;
    __syncthreads();
    if (tid == 0) {
        double v = (double)red[0] + (double)red[1] + (double)red[2] + (double)red[3];
        atomicAdd(acc_out, v);
    }
}

__global__ void cc3d_finalize(const double* __restrict__ acc, float* __restrict__ out)
{
    out[0] = (float)(-(acc[0] * INV_COUNT));
}

extern "C" void kernel_launch(void* const* d_in, const int* in_sizes, int n_in,
                              void* d_out, int out_size, void* d_ws, size_t ws_size,
                              hipStream_t stream)
{
    const float* in = (const float*)d_in[0];   // 'input'
    const float* tg = (const float*)d_in[1];   // 'target'
    const float* fl = (const float*)d_in[2];   // 'flow'
    float* out = (float*)d_out;
    double* acc = (double*)d_ws;

    hipMemsetAsync(d_ws, 0, sizeof(double), stream);  // graph-safe memset node

    dim3 grid(NW / TW, NH / TH, NB * NDCH);  // (10, 10, 10) = 1000 blocks
    cc3d_main<<<grid, dim3(256), 0, stream>>>(in, tg, fl, acc);
    cc3d_finalize<<<1, 1, 0, stream>>>(acc, out);
}

// Round 4
// 171.943 us; speedup vs baseline: 1.1413x; 1.0267x over previous
//
#include <hip/hip_runtime.h>

// crossCorrelation3D: local (9x9x9) normalized cross-correlation loss, fused.
// B=2, C=1, D=H=W=160, fp32. Output = -mean(cc), scalar.
//
// R4: barrier-region serialization is the residual cost (R3 post-mortem:
// nothing saturated, 1353 cyc/plane vs ~650 busiest-wave work; occupancy
// grid-capped at ~3.9 blocks/CU).
//  1. ONE barrier per plane: depth-3 pipeline, everything double-buffered.
//     iter l: stage(l) | step2(l-1) | hpass(l-2) | ring+cc(l-3) |
//     prefetch(l+1) | __syncthreads().  84 -> 43 barriers/block.
//     Hazards checked pairwise: every producer/consumer pair is on opposite
//     buffer parity or separated by >=1 barrier.
//  2. Phase->thread remap so no wave runs two heavy phases serially:
//     step2 [0,96), stage+prefetch [96,240), hpass [176,256).
//  3. LDS trimmed (TFS 484, PRS 16/PFS 264): 2x buffers = 39.2KB -> still
//     4 blocks/CU.
//
// NOTE: reference transforms target t=(raw+1)/2 BEFORE zero-padded box sum,
// so padding must contribute t=0. Transform applied at load time for
// in-bounds voxels; OOB D planes: stage/step2/hpass skipped (block-uniform),
// ring+cc substitutes pn=0 (never reads the stale buffer).

constexpr int NB = 2;
constexpr int ND = 160;
constexpr int NH = 160;
constexpr int NW = 160;
constexpr int TH = 16;
constexpr int TW = 16;
constexpr int DCHUNK = 32;
constexpr int NDCH = ND / DCHUNK;        // 5
constexpr int NPL = DCHUNK + 8;          // 40 planes per block
constexpr int NIT = NPL + 3;             // 43 pipeline iterations
constexpr int TRS = 20;                  // tmp5 row stride (floats, 80B)
constexpr int TFS = 24 * TRS + 4;        // 484: tmp5 field stride
constexpr int PRS = 16;                  // Pbuf row stride (reads: bank = tid mod 32, 2-way free)
constexpr int PFS = 16 * PRS + 8;        // 264: Pbuf field stride (mod 32 = 8)
constexpr float INV_K = 1.0f / 729.0f;
constexpr double INV_COUNT = 1.0 / (double(NB) * ND * NH * NW); // 1/8192000

// Issue global loads of one 24x24 halo plane (input & target) into registers.
// idx in [0,144): thread owns one float4 of the 24x(6*float4) plane. w0-4 is
// a multiple of 4 so rows are float4-aligned; each 4-wide segment is entirely
// in-bounds or entirely out (w0 % 16 == 0, halo = 4).
__device__ __forceinline__ void issue_load(
    const float* __restrict__ in, const float* __restrict__ tg,
    int b, int dp, int h0, int w0, int idx,
    float4& iv, float4& tv)
{
    iv = make_float4(0.f, 0.f, 0.f, 0.f);
    tv = make_float4(0.f, 0.f, 0.f, 0.f);
    if ((unsigned)idx < 144u && ((unsigned)dp < (unsigned)ND)) {
        int r = idx / 6;
        int q = idx - r * 6;
        int gh = h0 - 4 + r;
        int gw = w0 - 4 + q * 4;
        if (((unsigned)gh < (unsigned)NH) && ((unsigned)gw < (unsigned)NW)) {
            int base = ((b * ND + dp) * NH + gh) * NW + gw;   // fits int32
            iv = *reinterpret_cast<const float4*>(in + base);
            float4 rv = *reinterpret_cast<const float4*>(tg + base);
            tv.x = fmaf(rv.x, 0.5f, 0.5f);
            tv.y = fmaf(rv.y, 0.5f, 0.5f);
            tv.z = fmaf(rv.z, 0.5f, 0.5f);
            tv.w = fmaf(rv.w, 0.5f, 0.5f);
        }
    }
}

// w-direction 9-sums, quad form. Thread (r,q): outputs wo=4q..4q+3 of row r
// need inputs 4q..4q+11 (3 b128 per array). Register sliding per field.
#define W9SLIDE(EXPR, FI)                                                  \
    {                                                                      \
        float p0 = (EXPR(0)), p1 = (EXPR(1)), p2 = (EXPR(2)),              \
              p3 = (EXPR(3)), p4 = (EXPR(4)), p5 = (EXPR(5)),              \
              p6 = (EXPR(6)), p7 = (EXPR(7)), p8 = (EXPR(8)),              \
              p9 = (EXPR(9)), p10 = (EXPR(10)), p11 = (EXPR(11));          \
        float s = p0 + p1 + p2 + p3 + p4 + p5 + p6 + p7 + p8;              \
        float4 o;                                                          \
        o.x = s; s += p9 - p0;                                             \
        o.y = s; s += p10 - p1;                                            \
        o.z = s; s += p11 - p2;                                            \
        o.w = s;                                                           \
        *reinterpret_cast<float4*>(outp + (FI) * TFS) = o;                 \
    }

__device__ __forceinline__ void step2q(int tid, const float* __restrict__ inT,
                                       const float* __restrict__ tgT,
                                       float* __restrict__ t5)
{
    const int r = tid >> 2, q = tid & 3;
    const float4* ip = reinterpret_cast<const float4*>(inT + r * 24 + 4 * q);
    const float4* tp = reinterpret_cast<const float4*>(tgT + r * 24 + 4 * q);
    const float4 i0 = ip[0], i1 = ip[1], i2 = ip[2];
    const float4 t0 = tp[0], t1 = tp[1], t2 = tp[2];
    const float ia[12] = {i0.x, i0.y, i0.z, i0.w, i1.x, i1.y, i1.z, i1.w,
                          i2.x, i2.y, i2.z, i2.w};
    const float ta[12] = {t0.x, t0.y, t0.z, t0.w, t1.x, t1.y, t1.z, t1.w,
                          t2.x, t2.y, t2.z, t2.w};
    float* outp = t5 + r * TRS + 4 * q;
    #define E_T(j)  ta[j]
    #define E_I(j)  ia[j]
    #define E_TT(j) (ta[j] * ta[j])
    #define E_II(j) (ia[j] * ia[j])
    #define E_IT(j) (ia[j] * ta[j])
    W9SLIDE(E_T, 0)
    W9SLIDE(E_I, 1)
    W9SLIDE(E_TT, 2)
    W9SLIDE(E_II, 3)
    W9SLIDE(E_IT, 4)
    #undef E_T
    #undef E_I
    #undef E_TT
    #undef E_II
    #undef E_IT
}

// h-direction 9-sums, sliding quad form. t in [0,80): thread (f,wq,hs)
// produces ho=4hs..4hs+3 for field f, w-quad wq. Reads 12 rows as b128.
__device__ __forceinline__ void hpass(int t, const float* __restrict__ t5,
                                      float* __restrict__ Pb)
{
    const int f = t >> 4;
    const int rem = t & 15;
    const int wq = rem >> 2, hs = rem & 3;
    const float* bp = t5 + f * TFS + hs * 4 * TRS + wq * 4;
    float4 r4[12];
    #pragma unroll
    for (int k = 0; k < 12; ++k)
        r4[k] = *reinterpret_cast<const float4*>(bp + k * TRS);
    float sx = r4[0].x, sy = r4[0].y, sz = r4[0].z, sw = r4[0].w;
    #pragma unroll
    for (int k = 1; k < 9; ++k) {
        sx += r4[k].x; sy += r4[k].y; sz += r4[k].z; sw += r4[k].w;
    }
    float* op = Pb + f * PFS + hs * 4 * PRS + wq * 4;
    *reinterpret_cast<float4*>(op) = make_float4(sx, sy, sz, sw);
    #pragma unroll
    for (int j = 1; j < 4; ++j) {
        sx += r4[8 + j].x - r4[j - 1].x;
        sy += r4[8 + j].y - r4[j - 1].y;
        sz += r4[8 + j].z - r4[j - 1].z;
        sw += r4[8 + j].w - r4[j - 1].w;
        *reinterpret_cast<float4*>(op + j * PRS) = make_float4(sx, sy, sz, sw);
    }
}

__device__ __forceinline__ float cc_value(const float S[5], float flv)
{
    float wgt = 1.0f / (1.0f + __expf(-flv));   // sigmoid, GAMMA=1
    float Ts = S[0], Is = S[1], TTs = S[2], IIs = S[3], ITs = S[4];
    float Ihat = Is * INV_K;
    float That = Ts * INV_K;
    float cross = ITs - Ihat * Ts - That * Is + That * Ihat * 729.0f;
    float T_var = TTs - 2.0f * That * Ts + That * That * 729.0f;
    float I_var = IIs - 2.0f * Ihat * Is + Ihat * Ihat * 729.0f;
    return cross * cross * wgt / (T_var * I_var + 1e-5f);
}

__global__ void __launch_bounds__(256, 4)
cc3d_main(const float* __restrict__ in, const float* __restrict__ tg,
          const float* __restrict__ fl, double* __restrict__ acc_out)
{
    __shared__ __align__(16) float inT[2][24 * 24];
    __shared__ __align__(16) float tgT[2][24 * 24];
    __shared__ __align__(16) float tmp5[2][5 * TFS];
    __shared__ __align__(16) float Pb[2][5 * PFS];
    __shared__ float red[4];

    const int tid = threadIdx.x;
    const int w0 = blockIdx.x * TW;
    const int h0 = blockIdx.y * TH;
    const int bz = blockIdx.z;
    const int b  = bz / NDCH;
    const int d0 = (bz - b * NDCH) * DCHUNK;
    const int hh = tid >> 4, ww = tid & 15;
    const int sidx = tid - 96;               // stage/prefetch index [0,144)

    // D-direction ring of 9 plane values per field, statically indexed
    // (slot = (l-3) mod 9 = (li+6) mod 9, compile-time in unrolled li loop).
    float ring[45];
    #pragma unroll
    for (int i = 0; i < 45; ++i) ring[i] = 0.f;
    float S[5] = {0.f, 0.f, 0.f, 0.f, 0.f};
    float acc = 0.f;
    float flv = 0.f, flv_next = 0.f;

    // Prologue: loads for plane 0 (dp = d0-4) in flight on threads [96,240).
    float4 civ, ctv;
    issue_load(in, tg, b, d0 - 4, h0, w0, sidx, civ, ctv);

    // Single-barrier pipeline, depth 3.
    for (int lb = 0; lb < NIT; lb += 9) {     // lb = 0,9,18,27,36
        #pragma unroll
        for (int li = 0; li < 9; ++li) {
            const int l = lb + li;
            if (l < NIT) {                    // block-uniform
                // ---- stage plane l (regs from prev iter) -> inT[l&1] ----
                if (l < NPL) {
                    const int dpS = d0 - 4 + l;
                    if (((unsigned)dpS < (unsigned)ND) && (unsigned)sidx < 144u) {
                        reinterpret_cast<float4*>(inT[l & 1])[sidx] = civ;
                        reinterpret_cast<float4*>(tgT[l & 1])[sidx] = ctv;
                    }
                }
                // ---- step2 plane l-1: inT[(l-1)&1] -> tmp5[(l-1)&1] ----
                if (l >= 1 && l <= NPL) {
                    const int dp1 = d0 - 5 + l;
                    if (((unsigned)dp1 < (unsigned)ND) && tid < 96)
                        step2q(tid, inT[(l - 1) & 1], tgT[(l - 1) & 1],
                               tmp5[(l - 1) & 1]);
                }
                // ---- hpass plane l-2: tmp5[l&1] -> Pb[l&1] ----
                if (l >= 2 && l <= NPL + 1) {
                    const int dp2 = d0 - 6 + l;
                    if (((unsigned)dp2 < (unsigned)ND) && tid >= 176)
                        hpass(tid - 176, tmp5[l & 1], Pb[l & 1]);
                }
                // ---- ring + cc plane l-3 (Pb[(l-3)&1] = Pb[(l+1)&1]) ----
                if (l >= 3) {
                    const int lm3 = l - 3;
                    const int dp3 = d0 - 7 + l;
                    const bool vz = ((unsigned)dp3 < (unsigned)ND);  // uniform
                    const int slot = (li + 6) % 9;   // compile-time
                    const float* pb = Pb[(l + 1) & 1];
                    #pragma unroll
                    for (int f = 0; f < 5; ++f) {
                        float pn = vz ? pb[f * PFS + hh * PRS + ww] : 0.f;
                        S[f] += pn - ring[f * 9 + slot];
                        ring[f * 9 + slot] = pn;
                    }
                    if (lm3 >= 8) acc += cc_value(S, flv);
                }
                // ---- prefetch plane l+1 (regs) ----
                float4 niv = make_float4(0.f, 0.f, 0.f, 0.f), ntv = niv;
                if (l + 1 < NPL)
                    issue_load(in, tg, b, d0 - 3 + l, h0, w0, sidx, niv, ntv);
                // ---- flow prefetch for next iter's cc (plane l-2) ----
                if (l >= 10 && l <= 41) {
                    int dout = d0 + l - 10;
                    flv_next = fl[((b * ND + dout) * NH + (h0 + hh)) * NW + (w0 + ww)];
                }
                __syncthreads();
                civ = niv; ctv = ntv; flv = flv_next;
            }
        }
    }

    // ---- block reduction -> double atomic into workspace ----
    #pragma unroll
    for (int off = 32; off > 0; off >>= 1) acc += __shfl_down(acc, off);
    if ((tid & 63) == 0) red[tid >> 6] = acc;
    __syncthreads();
    if (tid == 0) {
        double v = (double)red[0] + (double)red[1] + (double)red[2] + (double)red[3];
        atomicAdd(acc_out, v);
    }
}

__global__ void cc3d_finalize(const double* __restrict__ acc, float* __restrict__ out)
{
    out[0] = (float)(-(acc[0] * INV_COUNT));
}

extern "C" void kernel_launch(void* const* d_in, const int* in_sizes, int n_in,
                              void* d_out, int out_size, void* d_ws, size_t ws_size,
                              hipStream_t stream)
{
    const float* in = (const float*)d_in[0];   // 'input'
    const float* tg = (const float*)d_in[1];   // 'target'
    const float* fl = (const float*)d_in[2];   // 'flow'
    float* out = (float*)d_out;
    double* acc = (double*)d_ws;

    hipMemsetAsync(d_ws, 0, sizeof(double), stream);  // graph-safe memset node

    dim3 grid(NW / TW, NH / TH, NB * NDCH);  // (10, 10, 10) = 1000 blocks
    cc3d_main<<<grid, dim3(256), 0, stream>>>(in, tg, fl, acc);
    cc3d_finalize<<<1, 1, 0, stream>>>(acc, out);
}